// Round 2
// baseline (663.253 us; speedup 1.0000x reference)
//
#include <hip/hip_runtime.h>

#define NN 256
#define CZ 128

typedef unsigned short u16;
typedef unsigned int u32;
typedef __attribute__((ext_vector_type(8))) short short8;
typedef __attribute__((ext_vector_type(4))) float f32x4;
typedef __attribute__((ext_vector_type(4))) u32 u32x4;

__device__ __forceinline__ float bf2f(u16 u){ u32 x = ((u32)u)<<16; float f; __builtin_memcpy(&f,&x,4); return f; }
__device__ __forceinline__ u16 f2bf(float f){ u32 u; __builtin_memcpy(&u,&f,4); u32 r = (u + 0x7fffu + ((u>>16)&1u))>>16; return (u16)r; }

__device__ __forceinline__ float wsum64(float v){
  #pragma unroll
  for (int m=32;m>=1;m>>=1) v += __shfl_xor(v,m,64);
  return v;
}
__device__ __forceinline__ float wsum32(float v){
  #pragma unroll
  for (int m=16;m>=1;m>>=1) v += __shfl_xor(v,m,64);
  return v;
}

// transpose+convert one 128x128 f32 weight: dst[n*128+k] = bf16(src[k*128+n])
__global__ __launch_bounds__(256) void kconv_t(const float* __restrict__ src, u16* __restrict__ dst){
  int t = blockIdx.x*256 + threadIdx.x;
  int n = t>>7, k = t&127;
  dst[n*128+k] = f2bf(src[k*128+n]);
}

// one wave per pair (i,j): dist->rbf->LN->dist_bias; shared edge LN -> zln(bf16) + third -> ebias
__global__ __launch_bounds__(256) void kprep(
    const float* __restrict__ ee, const float* __restrict__ coords,
    const float* __restrict__ w1, const float* __restrict__ rg, const float* __restrict__ rbta,
    const float* __restrict__ w2, const float* __restrict__ g3, const float* __restrict__ b3,
    const float* __restrict__ w3, const float* __restrict__ gs, const float* __restrict__ bs,
    u16* __restrict__ zln, float* __restrict__ ebias)
{
  int wid = (blockIdx.x*256 + threadIdx.x)>>6;
  int lane = threadIdx.x & 63;
  int i = wid>>8, j = wid&255;
  float dx = coords[i*3+0]-coords[j*3+0];
  float dy = coords[i*3+1]-coords[j*3+1];
  float dz = coords[i*3+2]-coords[j*3+2];
  float dist = sqrtf(dx*dx+dy*dy+dz*dz+1e-12f);
  // rbf: mu_r = 0.325 + 0.125*r (r<39), sigma = 4.75/39
  float rbv = 0.f;
  if (lane<39){ float t = (dist-(0.325f+0.125f*(float)lane))*8.210526315789474f; rbv = __expf(-t*t); }
  int c = lane&31;  // lanes 32..63 mirror lanes 0..31
  float hacc = 0.f;
  #pragma unroll
  for (int r=0;r<39;r++){ float rv = __shfl(rbv,r,64); hacc = fmaf(rv, w1[r*32+c], hacc); }
  float mu = wsum32(hacc)*(1.f/32.f);
  float vr = wsum32(hacc*hacc)*(1.f/32.f) - mu*mu;
  float hn = (hacc-mu)*rsqrtf(vr+1e-5f)*rg[c]+rbta[c];
  float db0 = wsum32(hn*w2[c*4+0]);
  float db1 = wsum32(hn*w2[c*4+1]);
  float db2 = wsum32(hn*w2[c*4+2]);
  float db3 = wsum32(hn*w2[c*4+3]);
  // edge LN (shared mean/var between s_ln and ln3)
  int c0 = lane*2, c1 = lane*2+1;
  float x0 = ee[(size_t)wid*128+c0], x1 = ee[(size_t)wid*128+c1];
  float m2 = wsum64(x0+x1)*(1.f/128.f);
  float v2 = wsum64(x0*x0+x1*x1)*(1.f/128.f)-m2*m2;
  float rinv = rsqrtf(v2+1e-5f);
  float n0 = (x0-m2)*rinv, n1 = (x1-m2)*rinv;
  u32 pk = (u32)f2bf(n0*gs[c0]+bs[c0]) | ((u32)f2bf(n1*gs[c1]+bs[c1])<<16);
  ((u32*)zln)[(size_t)wid*64+lane] = pk;
  float t0 = n0*g3[c0]+b3[c0], t1 = n1*g3[c1]+b3[c1];
  float th0 = wsum64(t0*w3[c0*4+0]+t1*w3[c1*4+0]);
  float th1 = wsum64(t0*w3[c0*4+1]+t1*w3[c1*4+1]);
  float th2 = wsum64(t0*w3[c0*4+2]+t1*w3[c1*4+2]);
  float th3 = wsum64(t0*w3[c0*4+3]+t1*w3[c1*4+3]);
  if (lane<4){
    float v = (lane==0)?(db0+th0):(lane==1)?(db1+th1):(lane==2)?(db2+th2):(db3+th3);
    ebias[(size_t)wid*4+lane] = v;
  }
}

// LN of z1 with e-params, written transposed: zln[j*256+i] = LN(z1[i*256+j])
__global__ __launch_bounds__(256) void klnt(const float* __restrict__ z1, const float* __restrict__ g,
                                            const float* __restrict__ b, u16* __restrict__ zln){
  int wid = (blockIdx.x*256+threadIdx.x)>>6;
  int lane = threadIdx.x&63;
  int a = wid>>8, bb = wid&255;
  int c0 = lane*2, c1 = c0+1;
  float x0 = z1[(size_t)wid*128+c0], x1 = z1[(size_t)wid*128+c1];
  float m = wsum64(x0+x1)*(1.f/128.f);
  float v = wsum64(x0*x0+x1*x1)*(1.f/128.f)-m*m;
  float rinv = rsqrtf(v+1e-5f);
  u32 pk = (u32)f2bf((x0-m)*rinv*g[c0]+b[c0]) | ((u32)f2bf((x1-m)*rinv*g[c1]+b[c1])<<16);
  ((u32*)zln)[((size_t)bb*256+a)*64+lane] = pk;
}

// zln[65536,128] @ wT[sel]  -> qkvg[65536,512] (sel 0=q,1=k,3=g(sigmoid)); sel2 -> vT transposed
__global__ __launch_bounds__(256) void kqkvg(const u16* __restrict__ zln, const u16* __restrict__ wT,
                                             u16* __restrict__ qkvg, u16* __restrict__ vT){
  const int m0 = blockIdx.x*128;
  const int sel = blockIdx.y;
  __shared__ u16 A[128*136];
  const int tid = threadIdx.x;
  #pragma unroll
  for (int r=0;r<8;r++){
    int chunk = tid + 256*r;            // 2048 chunks of 16B = 128 rows x 128 bf16
    int row = chunk>>4, off = (chunk&15)*8;
    *(u32x4*)&A[row*136+off] = *(const u32x4*)&zln[(size_t)(m0+row)*128+off];
  }
  __syncthreads();
  const int w = tid>>6, lane = tid&63, r16 = lane&15, gq = lane>>4;
  short8 a[2][4];
  #pragma unroll
  for (int mt=0;mt<2;mt++)
    #pragma unroll
    for (int ks=0;ks<4;ks++)
      a[mt][ks] = *(const short8*)&A[(w*32+mt*16+r16)*136 + ks*32 + gq*8];
  f32x4 acc[2][8];
  #pragma unroll
  for (int mt=0;mt<2;mt++)
    #pragma unroll
    for (int nt=0;nt<8;nt++)
      acc[mt][nt] = (f32x4){0.f,0.f,0.f,0.f};
  #pragma unroll
  for (int nt=0;nt<8;nt++){
    short8 bq[4];
    #pragma unroll
    for (int ks=0;ks<4;ks++)
      bq[ks] = *(const short8*)&wT[(size_t)(sel*128+nt*16+r16)*128 + ks*32 + gq*8];
    #pragma unroll
    for (int mt=0;mt<2;mt++)
      #pragma unroll
      for (int ks=0;ks<4;ks++)
        acc[mt][nt] = __builtin_amdgcn_mfma_f32_16x16x32_bf16(a[mt][ks], bq[ks], acc[mt][nt], 0,0,0);
  }
  #pragma unroll
  for (int mt=0;mt<2;mt++){
    int mb = m0 + w*32 + mt*16 + gq*4;
    #pragma unroll
    for (int nt=0;nt<8;nt++){
      int n = nt*16+r16;
      if (sel==2){
        u32 u0 = (u32)f2bf(acc[mt][nt][0]) | ((u32)f2bf(acc[mt][nt][1])<<16);
        u32 u1 = (u32)f2bf(acc[mt][nt][2]) | ((u32)f2bf(acc[mt][nt][3])<<16);
        int ii = mb>>8, j0 = mb&255;
        u32* dst = (u32*)&vT[(size_t)((ii*4+(n>>5))*32+(n&31))*256 + j0];
        dst[0]=u0; dst[1]=u1;
      } else {
        #pragma unroll
        for (int reg=0;reg<4;reg++){
          float v = acc[mt][nt][reg];
          if (sel==3) v = 1.f/(1.f+__expf(-v));
          qkvg[(size_t)(mb+reg)*512 + sel*128 + n] = f2bf(v);
        }
      }
    }
  }
}

// per (row i, head=wave, 4 q-tiles): S=QK^T (mfma) + bias, in-register softmax, P->LDS, PV (mfma), gate -> og
__global__ __launch_bounds__(256) void kattn(const u16* __restrict__ qkvg, const u16* __restrict__ vT,
                                             const float* __restrict__ ebias, const float* __restrict__ mask,
                                             u16* __restrict__ og, const int epass){
  const int i = blockIdx.x;
  const int qc = blockIdx.y;
  const int tid = threadIdx.x;
  const int h = tid>>6, lane = tid&63, r16 = lane&15, gq = lane>>4;
  __shared__ u16 P[4][16*264];
  float mb[16];
  #pragma unroll
  for (int kt=0;kt<16;kt++){
    int k = kt*16+r16;
    mb[kt] = (mask[epass ? k*256+i : i*256+k]-1.f)*1e8f;
  }
  const u16* qb = qkvg + (size_t)i*256*512;
  const u16* vb = vT + (size_t)(i*4+h)*32*256;
  for (int qt=qc*4; qt<qc*4+4; qt++){
    short8 aq = *(const short8*)&qb[(qt*16+r16)*512 + h*32 + gq*8];
    f32x4 s[16];
    #pragma unroll
    for (int kt=0;kt<16;kt++){
      short8 bk = *(const short8*)&qb[(kt*16+r16)*512 + 128 + h*32 + gq*8];
      f32x4 z = {0.f,0.f,0.f,0.f};
      s[kt] = __builtin_amdgcn_mfma_f32_16x16x32_bf16(aq, bk, z, 0,0,0);
    }
    #pragma unroll
    for (int kt=0;kt<16;kt++){
      int k = kt*16+r16;
      #pragma unroll
      for (int reg=0;reg<4;reg++){
        int q = qt*16+gq*4+reg;
        float bias = ebias[(size_t)(epass ? k*256+q : q*256+k)*4 + h];
        s[kt][reg] = fmaf(s[kt][reg], 0.17677669529663687f, bias + mb[kt]);
      }
    }
    #pragma unroll
    for (int reg=0;reg<4;reg++){
      float mx = -3e38f;
      #pragma unroll
      for (int kt=0;kt<16;kt++) mx = fmaxf(mx, s[kt][reg]);
      #pragma unroll
      for (int mm=1;mm<=8;mm<<=1) mx = fmaxf(mx, __shfl_xor(mx,mm,64));
      float sm = 0.f;
      #pragma unroll
      for (int kt=0;kt<16;kt++){ float p = __expf(s[kt][reg]-mx); s[kt][reg]=p; sm+=p; }
      #pragma unroll
      for (int mm=1;mm<=8;mm<<=1) sm += __shfl_xor(sm,mm,64);
      float iv = 1.f/sm;
      int row = gq*4+reg;
      #pragma unroll
      for (int kt=0;kt<16;kt++) P[h][row*264+kt*16+r16] = f2bf(s[kt][reg]*iv);
    }
    #pragma unroll
    for (int ct=0;ct<2;ct++){
      f32x4 o = {0.f,0.f,0.f,0.f};
      #pragma unroll
      for (int ks=0;ks<8;ks++){
        short8 ap = *(const short8*)&P[h][r16*264 + ks*32 + gq*8];
        short8 bv = *(const short8*)&vb[(ct*16+r16)*256 + ks*32 + gq*8];
        o = __builtin_amdgcn_mfma_f32_16x16x32_bf16(ap, bv, o, 0,0,0);
      }
      #pragma unroll
      for (int reg=0;reg<4;reg++){
        int q = qt*16+gq*4+reg, cc = ct*16+r16;
        float gv = bf2f(qb[(size_t)q*512 + 384 + h*32 + cc]);
        og[((size_t)i*256+q)*128 + h*32 + cc] = f2bf(o[reg]*gv);
      }
    }
  }
}

// og[65536,128] @ woT + residual -> out (epass: transposed scatter back to original frame)
__global__ __launch_bounds__(256) void kproj(const u16* __restrict__ og, const u16* __restrict__ woT,
                                             const float* __restrict__ resid, float* __restrict__ out,
                                             const int epass){
  const int m0 = blockIdx.x*128;
  __shared__ u16 A[128*136];
  const int tid = threadIdx.x;
  #pragma unroll
  for (int r=0;r<8;r++){
    int chunk = tid + 256*r;            // 2048 chunks of 16B = 128 rows x 128 bf16
    int row = chunk>>4, off = (chunk&15)*8;
    *(u32x4*)&A[row*136+off] = *(const u32x4*)&og[(size_t)(m0+row)*128+off];
  }
  __syncthreads();
  const int w = tid>>6, lane = tid&63, r16 = lane&15, gq = lane>>4;
  short8 a[2][4];
  #pragma unroll
  for (int mt=0;mt<2;mt++)
    #pragma unroll
    for (int ks=0;ks<4;ks++)
      a[mt][ks] = *(const short8*)&A[(w*32+mt*16+r16)*136 + ks*32 + gq*8];
  f32x4 acc[2][8];
  #pragma unroll
  for (int mt=0;mt<2;mt++)
    #pragma unroll
    for (int nt=0;nt<8;nt++)
      acc[mt][nt] = (f32x4){0.f,0.f,0.f,0.f};
  #pragma unroll
  for (int nt=0;nt<8;nt++){
    short8 bq[4];
    #pragma unroll
    for (int ks=0;ks<4;ks++)
      bq[ks] = *(const short8*)&woT[(size_t)(nt*16+r16)*128 + ks*32 + gq*8];
    #pragma unroll
    for (int mt=0;mt<2;mt++)
      #pragma unroll
      for (int ks=0;ks<4;ks++)
        acc[mt][nt] = __builtin_amdgcn_mfma_f32_16x16x32_bf16(a[mt][ks], bq[ks], acc[mt][nt], 0,0,0);
  }
  #pragma unroll
  for (int mt=0;mt<2;mt++){
    int mbase = m0+w*32+mt*16+gq*4;
    #pragma unroll
    for (int nt=0;nt<8;nt++){
      int n = nt*16+r16;
      #pragma unroll
      for (int reg=0;reg<4;reg++){
        int m = mbase+reg;
        size_t idx = epass ? ((size_t)((m&255)*256+(m>>8)))*128+(size_t)n : (size_t)m*128+(size_t)n;
        out[idx] = resid[idx] + acc[mt][nt][reg];
      }
    }
  }
}

extern "C" void kernel_launch(void* const* d_in, const int* in_sizes, int n_in,
                              void* d_out, int out_size, void* d_ws, size_t ws_size,
                              hipStream_t stream) {
  const float* ee     = (const float*)d_in[0];
  const float* coords = (const float*)d_in[1];
  const float* mask   = (const float*)d_in[2];
  const float* w1     = (const float*)d_in[3];
  const float* rg     = (const float*)d_in[4];
  const float* rbta   = (const float*)d_in[5];
  const float* w2     = (const float*)d_in[6];
  const float* g3     = (const float*)d_in[7];
  const float* b3     = (const float*)d_in[8];
  const float* w3     = (const float*)d_in[9];
  const float* sln_g  = (const float*)d_in[10];
  const float* sln_b  = (const float*)d_in[11];
  const float* eln_g  = (const float*)d_in[17];
  const float* eln_b  = (const float*)d_in[18];
  float* out = (float*)d_out;
  char* ws = (char*)d_ws;

  u16*   wT_s  = (u16*)(ws + 0);          // 512x128 bf16
  u16*   wT_e  = (u16*)(ws + 131072);
  u16*   woT_s = (u16*)(ws + 262144);     // 128x128 bf16
  u16*   woT_e = (u16*)(ws + 294912);
  float* ebias = (float*)(ws + 327680);   // [65536][4] f32
  u16*   zln   = (u16*)(ws + 1376256);    // [65536][128] bf16 (also reused as og)
  u16*   qkvg  = (u16*)(ws + 18153472);   // [65536][512] bf16
  u16*   vT    = (u16*)(ws + 85262336);   // [32768][256] bf16

  // weight prep
  for (int s=0;s<4;s++)
    kconv_t<<<64,256,0,stream>>>((const float*)d_in[12+s], wT_s + s*128*128);
  kconv_t<<<64,256,0,stream>>>((const float*)d_in[16], woT_s);
  for (int s=0;s<4;s++)
    kconv_t<<<64,256,0,stream>>>((const float*)d_in[19+s], wT_e + s*128*128);
  kconv_t<<<64,256,0,stream>>>((const float*)d_in[23], woT_e);

  // edge bias + z_ln (s)
  kprep<<<16384,256,0,stream>>>(ee, coords, w1, rg, rbta, w2, g3, b3, w3, sln_g, sln_b, zln, ebias);

  // ---- starting pass ----
  kqkvg<<<dim3(512,4),256,0,stream>>>(zln, wT_s, qkvg, vT);
  kattn<<<dim3(256,4),256,0,stream>>>(qkvg, vT, ebias, mask, zln /*og*/, 0);
  kproj<<<512,256,0,stream>>>(zln /*og*/, woT_s, ee, out, 0);

  // ---- ending pass (transposed frame) ----
  klnt<<<16384,256,0,stream>>>(out, eln_g, eln_b, zln);
  kqkvg<<<dim3(512,4),256,0,stream>>>(zln, wT_e, qkvg, vT);
  kattn<<<dim3(256,4),256,0,stream>>>(qkvg, vT, ebias, mask, zln /*og*/, 1);
  kproj<<<512,256,0,stream>>>(zln /*og*/, woT_e, out, out, 1);
}